// Round 1
// baseline (172.339 us; speedup 1.0000x reference)
//
#include <hip/hip_runtime.h>

// InformPooling, two-pass chunk-sum scheme, 16B/lane everywhere.
//   value0 [8,16384,128] r=1.0 ; value1 [8,8192,128] r=0.5 ; value2 [8,4096,256] r=0.25
//   start/duration [8,512]; out [8,512,512] f32 (channels concat 128|128|256).
//
// Pass 1 (chunk_sum): stream v once with dwordx4 loads, write sums of C=8 rows into d_ws.
//   Pools 0/1: one wave covers TWO chunks (16 rows, 8KB contiguous) via pair-row loads
//   (lane<32 = even row, lane>=32 = odd row), xor-32 shuffle folds halves, one 1KB store.
//   S0 [8][2048][128], S1 [8][1024][128], S2 [8][512][256]  -> 16.8 MB (L2/LLC-hot).
// Pass 2 (gather): per (b,n,pool) wave: interior = chunk-pair reads from S (1KB/instr),
//   edges = pair-row reads from v; xor-32 reduce; half-wave dwordx4 store.

constexpr int   kB   = 8;
constexpr int   kN   = 512;
constexpr float kEps = 1e-3f;
constexpr int   kC   = 8;  // chunk rows

// float offsets into ws
constexpr size_t S0_OFF = 0;                       // 8*2048*128
constexpr size_t S1_OFF = (size_t)8 * 2048 * 128;  // + 8*1024*128
constexpr size_t S2_OFF = S1_OFF + (size_t)8 * 1024 * 128;

__device__ __forceinline__ void acc4(float4& a, const float4 x) {
    a.x += x.x; a.y += x.y; a.z += x.z; a.w += x.w;
}

__device__ __forceinline__ float4 xor32_add(float4 a) {
    a.x += __shfl_xor(a.x, 32);
    a.y += __shfl_xor(a.y, 32);
    a.z += __shfl_xor(a.z, 32);
    a.w += __shfl_xor(a.w, 32);
    return a;
}

__global__ __launch_bounds__(256) void chunk_sum_kernel(
    const float* __restrict__ v0, const float* __restrict__ v1,
    const float* __restrict__ v2, float* __restrict__ ws)
{
    const int w    = (blockIdx.x * 256 + threadIdx.x) >> 6;  // global wave id
    const int lane = threadIdx.x & 63;

    if (w < 8192) {                        // pool0: b*1024 chunk-PAIRS (16 rows = 8KB)
        const int b = w >> 10, pr = w & 1023;
        const float4* p = (const float4*)v0
            + ((size_t)b * 16384 + (size_t)pr * 16) * 32 + lane;
        float4 a0 = make_float4(0.f, 0.f, 0.f, 0.f);
        float4 a1 = make_float4(0.f, 0.f, 0.f, 0.f);
#pragma unroll
        for (int j = 0; j < 4; j++) acc4(a0, p[j * 64]);       // chunk 2*pr rows
#pragma unroll
        for (int j = 4; j < 8; j++) acc4(a1, p[j * 64]);       // chunk 2*pr+1 rows
        a0 = xor32_add(a0);                                     // fold even/odd rows
        a1 = xor32_add(a1);
        float4 v = (lane < 32) ? a0 : a1;                       // lanes 0-31: chunk 2pr
        ((float4*)(ws + S0_OFF))[((size_t)b * 2048 + (size_t)pr * 2) * 32 + lane] = v;
    } else if (w < 12288) {                // pool1: b*512 chunk-pairs
        const int idx = w - 8192;
        const int b = idx >> 9, pr = idx & 511;
        const float4* p = (const float4*)v1
            + ((size_t)b * 8192 + (size_t)pr * 16) * 32 + lane;
        float4 a0 = make_float4(0.f, 0.f, 0.f, 0.f);
        float4 a1 = make_float4(0.f, 0.f, 0.f, 0.f);
#pragma unroll
        for (int j = 0; j < 4; j++) acc4(a0, p[j * 64]);
#pragma unroll
        for (int j = 4; j < 8; j++) acc4(a1, p[j * 64]);
        a0 = xor32_add(a0);
        a1 = xor32_add(a1);
        float4 v = (lane < 32) ? a0 : a1;
        ((float4*)(ws + S1_OFF))[((size_t)b * 1024 + (size_t)pr * 2) * 32 + lane] = v;
    } else if (w < 16384) {                // pool2: b*512 chunks, 256 ch (1KB rows)
        const int idx = w - 12288;
        const int b = idx >> 9, tc = idx & 511;
        const float4* p = (const float4*)v2
            + ((size_t)b * 4096 + (size_t)tc * kC) * 64 + lane;
        float4 a0 = make_float4(0.f, 0.f, 0.f, 0.f);
        float4 a1 = make_float4(0.f, 0.f, 0.f, 0.f);
#pragma unroll
        for (int i = 0; i < 4; i++) acc4(a0, p[i * 64]);
#pragma unroll
        for (int i = 4; i < 8; i++) acc4(a1, p[i * 64]);
        acc4(a0, a1);
        ((float4*)(ws + S2_OFF))[((size_t)b * 512 + (size_t)tc) * 64 + lane] = a0;
    }
}

__global__ __launch_bounds__(256) void gather_kernel(
    const float* __restrict__ v0, const float* __restrict__ v1,
    const float* __restrict__ v2, const float* __restrict__ start,
    const float* __restrict__ dur, const float* __restrict__ ws,
    float* __restrict__ out)
{
    const int wave    = threadIdx.x >> 6;
    const int lane    = threadIdx.x & 63;
    const int lane_lo = lane & 31;
    const int hi      = lane >> 5;
    const int bn      = blockIdx.x * 4 + wave;   // [0, 4096)
    const int b       = bn >> 9;
    const int pool    = blockIdx.y;

    const float st = start[bn];
    const float du = dur[bn];
    float* outbase = out + (size_t)bn * 512;

    if (pool < 2) {
        const float*  v  = (pool == 0) ? v0 : v1;
        const float*  S  = ws + ((pool == 0) ? S0_OFF : S1_OFF);
        const int     T  = (pool == 0) ? 16384 : 8192;
        const int     NC = T / kC;
        const float   r  = (pool == 0) ? 1.0f : 0.5f;
        const int s = min((int)floorf(st * r), T - 1);
        const int e = min((int)ceilf((st + du + kEps) * r), T - 1);
        const int cnt = e - s;

        float4 a0 = make_float4(0.f, 0.f, 0.f, 0.f);
        float4 a1 = make_float4(0.f, 0.f, 0.f, 0.f);
        if (cnt > 0) {
            // row t occupies float4s [t*32, t*32+32); pair load: lane<32 row t, lane>=32 row t+1
            const float4* vp = (const float4*)v + (size_t)b * T * 32;
            const int cs = (s + kC - 1) >> 3;
            const int ce = e >> 3;
            if (ce > cs) {
                const float4* Sp = (const float4*)S + (size_t)b * NC * 32;
                int c = cs;
                for (; c + 4 <= ce; c += 4) {                  // interior, 4 chunks/iter
                    acc4(a0, Sp[(size_t)c * 32 + lane]);
                    acc4(a1, Sp[(size_t)(c + 2) * 32 + lane]);
                }
                if (c + 2 <= ce) { acc4(a0, Sp[(size_t)c * 32 + lane]); c += 2; }
                if (c < ce) {                                  // odd tail chunk: hi half masked
                    float4 x = Sp[(size_t)c * 32 + lane];      // chunk c+1 <= ce <= NC-1: in-bounds
                    if (hi == 0) acc4(a0, x);
                }
                const int fe = cs << 3;
                for (int t = s; t < fe; t += 2) {              // front edge (<=7 rows)
                    float4 x = vp[(size_t)t * 32 + lane];      // row t+1 <= fe <= T-8: in-bounds
                    if (hi == 0 || t + 1 < fe) acc4(a0, x);
                }
                const int be = ce << 3;
                for (int t = be; t < e; t += 2) {              // back edge (<=7 rows)
                    float4 x = vp[(size_t)t * 32 + lane];      // row t+1 <= e <= T-1: in-bounds
                    if (hi == 0 || t + 1 < e) acc4(a1, x);
                }
            } else {
                for (int t = s; t < e; t += 2) {               // short segment (<=15 rows)
                    float4 x = vp[(size_t)t * 32 + lane];
                    if (hi == 0 || t + 1 < e) acc4(a0, x);
                }
            }
        }
        float4 res = make_float4(0.f, 0.f, 0.f, 0.f);
        if (cnt > 0) {
            acc4(a0, a1);
            a0 = xor32_add(a0);                                // fold row-t / row-t+1 halves
            const float inv = 1.0f / (float)cnt;
            res.x = a0.x * inv; res.y = a0.y * inv;
            res.z = a0.z * inv; res.w = a0.w * inv;
        }
        if (hi == 0)
            ((float4*)(outbase + (pool == 0 ? 0 : 128)))[lane_lo] = res;
    } else {
        const int   T  = 4096;
        const int   NC = T / kC;
        const float r  = 0.25f;
        const int s = min((int)floorf(st * r), T - 1);
        const int e = min((int)ceilf((st + du + kEps) * r), T - 1);
        const int cnt = e - s;

        float4 a0 = make_float4(0.f, 0.f, 0.f, 0.f);
        float4 a1 = make_float4(0.f, 0.f, 0.f, 0.f);
        if (cnt > 0) {
            const float4* vp = (const float4*)v2 + (size_t)b * T * 64 + lane;
            const int cs = (s + kC - 1) >> 3;
            const int ce = e >> 3;
            if (ce > cs) {
                const float4* Sp = (const float4*)(ws + S2_OFF) + (size_t)b * NC * 64 + lane;
                int c = cs;
                for (; c + 4 <= ce; c += 4) {                  // interior, 4 chunks/iter
                    acc4(a0, Sp[(size_t)c * 64]);
                    acc4(a1, Sp[(size_t)(c + 1) * 64]);
                    acc4(a0, Sp[(size_t)(c + 2) * 64]);
                    acc4(a1, Sp[(size_t)(c + 3) * 64]);
                }
                for (; c < ce; ++c) acc4(a0, Sp[(size_t)c * 64]);
                for (int t = s; t < cs * kC; ++t) acc4(a0, vp[(size_t)t * 64]);
                for (int t = ce * kC; t < e; ++t) acc4(a1, vp[(size_t)t * 64]);
            } else {
                for (int t = s; t < e; ++t) acc4(a0, vp[(size_t)t * 64]);
            }
        }
        float4 res = make_float4(0.f, 0.f, 0.f, 0.f);
        if (cnt > 0) {
            acc4(a0, a1);
            const float inv = 1.0f / (float)cnt;
            res.x = a0.x * inv; res.y = a0.y * inv;
            res.z = a0.z * inv; res.w = a0.w * inv;
        }
        ((float4*)(outbase + 256))[lane] = res;
    }
}

extern "C" void kernel_launch(void* const* d_in, const int* in_sizes, int n_in,
                              void* d_out, int out_size, void* d_ws, size_t ws_size,
                              hipStream_t stream) {
    const float* v0    = (const float*)d_in[0];
    const float* v1    = (const float*)d_in[1];
    const float* v2    = (const float*)d_in[2];
    const float* start = (const float*)d_in[3];
    const float* dur   = (const float*)d_in[4];
    float*       out   = (float*)d_out;
    float*       ws    = (float*)d_ws;

    // Pass 1: 16384 waves (8192 + 4096 + 4096), 4 waves/block
    chunk_sum_kernel<<<dim3(16384 / 4), 256, 0, stream>>>(v0, v1, v2, ws);
    // Pass 2: one wave per (bn, pool)
    gather_kernel<<<dim3(kB * kN / 4, 3), 256, 0, stream>>>(v0, v1, v2, start, dur, ws, out);
}